// Round 11
// baseline (21349.074 us; speedup 1.0000x reference)
//
#include <hip/hip_runtime.h>

#define BB 32
#define SS 64
#define TT 64
#define VV 32000
#define EE 512
#define HH 1024
#define GRID 512
#define BLK 512
#define NFC 500          // FC tiles of 64 j
#define ASTR 16          // barrier slot stride in ints (64B)
#define FLTMAX 3.402823466e38f

typedef unsigned long long u64;
typedef float f32x4 __attribute__((ext_vector_type(4)));

struct Par {
  const int *src, *tgt, *tmask;
  const float *enc_embed, *dec_embed;
  const float *enc_wih0, *enc_whh0, *enc_b0;
  const float *enc_wih1, *enc_whh1, *enc_b1;
  const float *dec_wih0, *dec_whh0, *dec_b0;
  const float *dec_wih1, *dec_whh1, *dec_b1;
  const float *fc_w, *fc_b;
  float *out;
  float *hA0, *hA1;               // layer-0 h double buffer (coherent)
  float *hBall;                   // 64 slots x [32][1024] h-history (coherent)
  float *cA, *cB;                 // block-private cell state
  float2 *cand;                   // [500][32]
  int *tok;                       // [32]
  int *arr; int *gen;
};

__device__ __forceinline__ float sigf(float x) { return 1.0f / (1.0f + expf(-x)); }

// ---- coherent agent-scope RELAXED access (no L2-invalidate fences) --------
__device__ __forceinline__ float2 ldc2(const float* p) {
  u64 v = __hip_atomic_load((const u64*)p, __ATOMIC_RELAXED, __HIP_MEMORY_SCOPE_AGENT);
  union { u64 u; float2 f; } c; c.u = v; return c.f;
}
__device__ __forceinline__ void stc2(float* p, float x, float y) {
  union { u64 u; float2 f; } c; c.f = make_float2(x, y);
  __hip_atomic_store((u64*)p, c.u, __ATOMIC_RELAXED, __HIP_MEMORY_SCOPE_AGENT);
}
__device__ __forceinline__ void stc1(float* p, float x) {
  __hip_atomic_store(p, x, __ATOMIC_RELAXED, __HIP_MEMORY_SCOPE_AGENT);
}
__device__ __forceinline__ int ldci(const int* p) {
  return __hip_atomic_load(p, __ATOMIC_RELAXED, __HIP_MEMORY_SCOPE_AGENT);
}

// ---------------------------------------------------------------------------
// Fence-free grid barrier: 64B-stride arrival slots, 16 replicated gen lines,
// exponential-backoff polling. REQUIRES all 512 blocks co-resident.
// ---------------------------------------------------------------------------
__device__ __forceinline__ void gbar(int* arr, int* gen, int target) {
  __syncthreads();
  asm volatile("s_waitcnt vmcnt(0)" ::: "memory");
  if (blockIdx.x == 0) {
    if (threadIdx.x < 64) {
      const int s = threadIdx.x;
      int spin = 0;
      for (;;) {
        bool ok = true;
#pragma unroll
        for (int o = 0; o < GRID; o += 64) {
          int idx = s + o;
          int a = (idx == 0) ? target
              : __hip_atomic_load(arr + idx * ASTR, __ATOMIC_RELAXED, __HIP_MEMORY_SCOPE_AGENT);
          ok &= (a >= target);
        }
        if (__all(ok)) break;
        if (spin < 8) __builtin_amdgcn_s_sleep(1);
        else          __builtin_amdgcn_s_sleep(8);
        ++spin;
      }
    }
    __syncthreads();
    if (threadIdx.x < 16)
      __hip_atomic_store(gen + threadIdx.x * ASTR, target, __ATOMIC_RELAXED, __HIP_MEMORY_SCOPE_AGENT);
  } else {
    if (threadIdx.x == 0) {
      __hip_atomic_store(arr + blockIdx.x * ASTR, target, __ATOMIC_RELAXED, __HIP_MEMORY_SCOPE_AGENT);
      int spin = 0;
      while (__hip_atomic_load(gen + (blockIdx.x & 15) * ASTR, __ATOMIC_RELAXED, __HIP_MEMORY_SCOPE_AGENT) < target) {
        if (spin < 4)       __builtin_amdgcn_s_sleep(1);
        else if (spin < 16) __builtin_amdgcn_s_sleep(8);
        else                __builtin_amdgcn_s_sleep(32);
        ++spin;
      }
    }
    __syncthreads();
  }
  asm volatile("" ::: "memory");
}

// ---------------------------------------------------------------------------
// LSTM partial accumulate (u-tile 4 -> 16 gate rows, acc[16]); weights staged
// via LDS (coalesced 1KB/instr), read back as 2-way-broadcast b128 (free).
// Threads: b = tid&31, tc = tid>>5 (16 k-slices of 16 per 256-chunk).
// ---------------------------------------------------------------------------
__device__ __forceinline__ void lstm_accum(
    const float* __restrict__ tab, const int* __restrict__ stokL,
    const float* __restrict__ xcoh, int lenx,
    const float* __restrict__ W, int u0,
    float* __restrict__ acc, float* __restrict__ wbuf)
{
  const int tid = threadIdx.x;
  const int b = tid & 31, tc = tid >> 5;
  const int lane = tid & 63, wid = tid >> 6;
  const int r2 = wid + 8;
  const float* wr1 = W + (size_t)((wid >> 2) * HH + u0 + (wid & 3)) * lenx + (lane << 2);
  const float* wr2 = W + (size_t)((r2  >> 2) * HH + u0 + (r2  & 3)) * lenx + (lane << 2);
  const int ncx = lenx >> 8;
  for (int c = 0; c < ncx; ++c) {
    const int col = c << 8;
    __syncthreads();
    {
      float4 wA = *reinterpret_cast<const float4*>(wr1 + col);
      float4 wB = *reinterpret_cast<const float4*>(wr2 + col);
      *reinterpret_cast<float4*>(wbuf + (wid << 8) + (lane << 2)) = wA;
      *reinterpret_cast<float4*>(wbuf + (r2  << 8) + (lane << 2)) = wB;
    }
    float xr[16];
    if (tab) {
      const int tk = stokL[b];
      if (tk) {
        const float4* s4 = reinterpret_cast<const float4*>(
            tab + (size_t)tk * lenx + col + (tc << 4));
#pragma unroll
        for (int e = 0; e < 4; ++e) {
          float4 v = s4[e];
          xr[e*4] = v.x; xr[e*4+1] = v.y; xr[e*4+2] = v.z; xr[e*4+3] = v.w;
        }
      } else {
#pragma unroll
        for (int e = 0; e < 16; ++e) xr[e] = 0.f;
      }
    } else {
      const float* xp = xcoh + (size_t)b * lenx + col + (tc << 4);
#pragma unroll
      for (int e = 0; e < 8; ++e) {
        float2 v = ldc2(xp + 2*e); xr[2*e] = v.x; xr[2*e+1] = v.y;
      }
    }
    __syncthreads();
#pragma unroll
    for (int q = 0; q < 16; ++q) {
      const float4* w4 = reinterpret_cast<const float4*>(wbuf + (q << 8) + (tc << 4));
      float4 w0 = w4[0], w1 = w4[1], w2 = w4[2], w3 = w4[3];
      acc[q] += xr[0]*w0.x + xr[1]*w0.y + xr[2]*w0.z + xr[3]*w0.w
              + xr[4]*w1.x + xr[5]*w1.y + xr[6]*w1.z + xr[7]*w1.w
              + xr[8]*w2.x + xr[9]*w2.y + xr[10]*w2.z + xr[11]*w2.w
              + xr[12]*w3.x + xr[13]*w3.y + xr[14]*w3.z + xr[15]*w3.w;
    }
  }
}

// cross-slice reduce + cell + coherent h-store (red at SH+4096)
__device__ __forceinline__ void lstm_finish(
    const float* __restrict__ bias, int u0,
    const float* __restrict__ acc, float* __restrict__ cpriv,
    float* __restrict__ hdst, float* __restrict__ SH)
{
  const int tid = threadIdx.x;
  const int b = tid & 31, tc = tid >> 5;
  float* red = SH + 4096;
  __syncthreads();
#pragma unroll
  for (int q = 0; q < 16; ++q) red[(tc * 16 + q) * 33 + b] = acc[q];
  __syncthreads();
  if (tid < 128) {
    int bb = tid & 31, ul = tid >> 5;
    float g[4];
#pragma unroll
    for (int gg = 0; gg < 4; ++gg) {
      float s = bias[gg * HH + u0 + ul];
#pragma unroll
      for (int t2 = 0; t2 < 16; ++t2) s += red[(t2 * 16 + gg * 4 + ul) * 33 + bb];
      g[gg] = s;
    }
    float cn = sigf(g[1]) * cpriv[(bb << 2) + ul] + sigf(g[0]) * tanhf(g[2]);
    float hn = sigf(g[3]) * tanhf(cn);
    cpriv[(bb << 2) + ul] = cn;
    stc1(hdst + (size_t)bb * HH + u0 + ul, hn);
  }
  __syncthreads();
}

// ---------------------------------------------------------------------------
// FC tile, NT time-steps per pass (weights reused in REGISTERS across t).
// Thread: jl=tid&15 -> 4 j's; bg=(tid>>4)&15 -> 2 b's; kh=tid>>8 -> k-half of
// each 128-chunk. acc[8*NT] (<=16). Weights: nontemporal (evict-first) loads,
// lane-distinct rows (16 lines/instr). h broadcast from LDS [32][136] per t.
// ---------------------------------------------------------------------------
template<int NT>
__device__ __forceinline__ void fc_dot(const Par& p,
    const float* __restrict__ h0, const float* __restrict__ h1,
    int t0, int t1, int fcid, float* __restrict__ SH, bool do_am)
{
  const int tid = threadIdx.x;
  const int jl = tid & 15;
  const int bg = (tid >> 4) & 15;
  const int kh = tid >> 8;
  const int jbase = fcid * 64;
  const int j0 = jbase + (jl << 2);
  const float* w0 = p.fc_w + (size_t)j0 * HH;
  const float* w1 = w0 + HH;
  const float* w2 = w1 + HH;
  const float* w3 = w2 + HH;
  float acc[8 * NT];
#pragma unroll
  for (int q = 0; q < 8 * NT; ++q) acc[q] = 0.f;

  for (int c = 0; c < 8; ++c) {
    __syncthreads();
    {   // stage [32][128] per t -> SH[t*4352 + row*136 + col]
      int sb = tid >> 4, cg = (tid & 15) << 3;
      const float* xp0 = h0 + (size_t)sb * HH + (c << 7) + cg;
      float* d0 = SH + sb * 136 + cg;
#pragma unroll
      for (int e = 0; e < 4; ++e) {
        float2 v = ldc2(xp0 + 2 * e); d0[2*e] = v.x; d0[2*e+1] = v.y;
      }
      if constexpr (NT == 2) {
        const float* xp1 = h1 + (size_t)sb * HH + (c << 7) + cg;
        float* d1 = SH + 4352 + sb * 136 + cg;
#pragma unroll
        for (int e = 0; e < 4; ++e) {
          float2 v = ldc2(xp1 + 2 * e); d1[2*e] = v.x; d1[2*e+1] = v.y;
        }
      }
    }
    __syncthreads();
    const int kb = (c << 7) + (kh << 6);
    const float* pw0 = w0 + kb; const float* pw1 = w1 + kb;
    const float* pw2 = w2 + kb; const float* pw3 = w3 + kb;
    const float* px0 = SH + ((bg << 1) * 136) + (kh << 6);
    const float* px1 = SH + 4352 + ((bg << 1) * 136) + (kh << 6);
#pragma unroll 4
    for (int kk = 0; kk < 64; kk += 4) {
      f32x4 a0 = __builtin_nontemporal_load(reinterpret_cast<const f32x4*>(pw0 + kk));
      f32x4 a1 = __builtin_nontemporal_load(reinterpret_cast<const f32x4*>(pw1 + kk));
      f32x4 a2 = __builtin_nontemporal_load(reinterpret_cast<const f32x4*>(pw2 + kk));
      f32x4 a3 = __builtin_nontemporal_load(reinterpret_cast<const f32x4*>(pw3 + kk));
      float4 xA = *reinterpret_cast<const float4*>(px0 + kk);
      float4 xB = *reinterpret_cast<const float4*>(px0 + 136 + kk);
      acc[0] += a0.x*xA.x + a0.y*xA.y + a0.z*xA.z + a0.w*xA.w;
      acc[1] += a1.x*xA.x + a1.y*xA.y + a1.z*xA.z + a1.w*xA.w;
      acc[2] += a2.x*xA.x + a2.y*xA.y + a2.z*xA.z + a2.w*xA.w;
      acc[3] += a3.x*xA.x + a3.y*xA.y + a3.z*xA.z + a3.w*xA.w;
      acc[4] += a0.x*xB.x + a0.y*xB.y + a0.z*xB.z + a0.w*xB.w;
      acc[5] += a1.x*xB.x + a1.y*xB.y + a1.z*xB.z + a1.w*xB.w;
      acc[6] += a2.x*xB.x + a2.y*xB.y + a2.z*xB.z + a2.w*xB.w;
      acc[7] += a3.x*xB.x + a3.y*xB.y + a3.z*xB.z + a3.w*xB.w;
      if constexpr (NT == 2) {
        float4 yA = *reinterpret_cast<const float4*>(px1 + kk);
        float4 yB = *reinterpret_cast<const float4*>(px1 + 136 + kk);
        acc[8]  += a0.x*yA.x + a0.y*yA.y + a0.z*yA.z + a0.w*yA.w;
        acc[9]  += a1.x*yA.x + a1.y*yA.y + a1.z*yA.z + a1.w*yA.w;
        acc[10] += a2.x*yA.x + a2.y*yA.y + a2.z*yA.z + a2.w*yA.w;
        acc[11] += a3.x*yA.x + a3.y*yA.y + a3.z*yA.z + a3.w*yA.w;
        acc[12] += a0.x*yB.x + a0.y*yB.y + a0.z*yB.z + a0.w*yB.w;
        acc[13] += a1.x*yB.x + a1.y*yB.y + a1.z*yB.z + a1.w*yB.w;
        acc[14] += a2.x*yB.x + a2.y*yB.y + a2.z*yB.z + a2.w*yB.w;
        acc[15] += a3.x*yB.x + a3.y*yB.y + a3.z*yB.z + a3.w*yB.w;
      }
    }
  }
  // k-half reduce at SH+8704 [256][17]
  float* red2 = SH + 8704;
  __syncthreads();
  if (kh == 1) {
    int s = tid - 256;
#pragma unroll
    for (int e = 0; e < 8 * NT; ++e) red2[s * 17 + e] = acc[e];
  }
  __syncthreads();
  if (kh == 0) {
#pragma unroll
    for (int e = 0; e < 8 * NT; ++e) acc[e] += red2[tid * 17 + e];
    float b0 = p.fc_b[j0], b1 = p.fc_b[j0+1], b2 = p.fc_b[j0+2], b3 = p.fc_b[j0+3];
    const int rb0 = bg << 1, rb1 = rb0 + 1;
    float4 vA = make_float4(acc[0]+b0, acc[1]+b1, acc[2]+b2, acc[3]+b3);
    float4 vB = make_float4(acc[4]+b0, acc[5]+b1, acc[6]+b2, acc[7]+b3);
    *reinterpret_cast<float4*>(p.out + (size_t)rb0 * TT * VV + (size_t)t0 * VV + j0) = vA;
    *reinterpret_cast<float4*>(p.out + (size_t)rb1 * TT * VV + (size_t)t0 * VV + j0) = vB;
    if constexpr (NT == 2) {
      float4 wA = make_float4(acc[8]+b0, acc[9]+b1, acc[10]+b2, acc[11]+b3);
      float4 wB = make_float4(acc[12]+b0, acc[13]+b1, acc[14]+b2, acc[15]+b3);
      *reinterpret_cast<float4*>(p.out + (size_t)rb0 * TT * VV + (size_t)t1 * VV + j0) = wA;
      *reinterpret_cast<float4*>(p.out + (size_t)rb1 * TT * VV + (size_t)t1 * VV + j0) = wB;
    }
    if (do_am) {   // per-(b, jl) first-max over this thread's 4 j
      float2* SA = reinterpret_cast<float2*>(SH + 13056);   // [32][16]
      float mA = acc[0] + b0; int iA = j0;
      if (acc[1]+b1 > mA) { mA = acc[1]+b1; iA = j0+1; }
      if (acc[2]+b2 > mA) { mA = acc[2]+b2; iA = j0+2; }
      if (acc[3]+b3 > mA) { mA = acc[3]+b3; iA = j0+3; }
      float mB = acc[4] + b0; int iB = j0;
      if (acc[5]+b1 > mB) { mB = acc[5]+b1; iB = j0+1; }
      if (acc[6]+b2 > mB) { mB = acc[6]+b2; iB = j0+2; }
      if (acc[7]+b3 > mB) { mB = acc[7]+b3; iB = j0+3; }
      SA[rb0 * 16 + jl] = make_float2(mA, __int_as_float(iA));
      SA[rb1 * 16 + jl] = make_float2(mB, __int_as_float(iB));
    }
  }
  __syncthreads();
  if (do_am && tid < 32) {
    float2* SA = reinterpret_cast<float2*>(SH + 13056);
    float bv = -FLTMAX; int bi = 0x7fffffff;
#pragma unroll
    for (int s2 = 0; s2 < 16; ++s2) {
      float2 cv = SA[tid * 16 + s2]; int ci = __float_as_int(cv.y);
      if (cv.x > bv || (cv.x == bv && ci < bi)) { bv = cv.x; bi = ci; }
    }
    stc2((float*)&p.cand[fcid * 32 + tid], bv, __int_as_float(bi));
  }
  __syncthreads();
}

// AMred: block b (0..31) reduces 500 candidates -> p.tok[b] (argmax steps only)
__device__ __forceinline__ void amred(const Par& p, float* SH)
{
  const int tid = threadIdx.x;
  const int b = blockIdx.x;
  float bv = -FLTMAX; int bi = 0x7fffffff;
  if (tid < NFC) {
    float2 cv = ldc2((const float*)&p.cand[tid * 32 + b]);
    bv = cv.x; bi = __float_as_int(cv.y);
  }
  float* sv = SH; int* si = (int*)(SH + 512);
  sv[tid] = bv; si[tid] = bi;
  __syncthreads();
  for (int s = 256; s > 0; s >>= 1) {
    if (tid < s) {
      float ov = sv[tid + s]; int oi = si[tid + s];
      if (ov > sv[tid] || (ov == sv[tid] && oi < si[tid])) { sv[tid] = ov; si[tid] = oi; }
    }
    __syncthreads();
  }
  if (tid == 0)
    __hip_atomic_store(p.tok + b, si[0], __ATOMIC_RELAXED, __HIP_MEMORY_SCOPE_AGENT);
}

// ---------------------------------------------------------------------------
__global__ void __attribute__((amdgpu_waves_per_eu(4, 4))) __launch_bounds__(BLK)
mega(Par p) {
  __shared__ __attribute__((aligned(16))) float SH[14336];  // 57.3KB -> 2 blocks/CU (LDS-limited)
  __shared__ int stok[32];

  const int tid = threadIdx.x;
  const int bid = blockIdx.x;
  const int gid = bid * BLK + tid;
  int gen = 0;

  // ---- init
  for (int i = gid * 2; i < 2 * BB * HH; i += GRID * BLK * 2)
    stc2(p.hA0 + i, 0.f, 0.f);                       // hA0,hA1 contiguous
  for (int i = gid * 2; i < 2 * BB * HH; i += GRID * BLK * 2)
    stc2(p.hBall + 62 * BB * HH + i, 0.f, 0.f);      // hB slots 62,63 (enc ping-pong)
  if (tid < 128) {
    if (bid < 256) p.cA[bid * 128 + tid] = 0.f;
    else           p.cB[(bid - 256) * 128 + tid] = 0.f;
  }
  for (long g2 = gid; g2 < (long)BB * VV; g2 += (long)GRID * BLK) {
    int b = (int)(g2 / VV), v = (int)(g2 - (long)b * VV);
    __builtin_nontemporal_store(0.f, p.out + (size_t)b * TT * VV + v);
  }
  gbar(p.arr, p.gen, ++gen);

  // ---- encoder: L0(tt) on blocks 0..255 || L1(tt-1) on 256..511
  for (int tt = 0; tt <= SS; ++tt) {
    const int par = tt & 1;
    float* hA_w = par ? p.hA1 : p.hA0;
    float* hA_r = par ? p.hA0 : p.hA1;
    if (bid < 256) {
      if (tt < SS) {
        if (tid < 32) stok[tid] = p.src[tid * SS + tt];
        __syncthreads();
        const int u0 = bid * 4;
        float acc[16] = {0.f};
        lstm_accum(p.enc_embed, stok, nullptr, EE, p.enc_wih0, u0, acc, SH);
        lstm_accum(nullptr, nullptr, hA_r, HH, p.enc_whh0, u0, acc, SH);
        lstm_finish(p.enc_b0, u0, acc, p.cA + bid * 128, hA_w, SH);
      }
    } else {
      if (tt >= 1) {
        const int te = tt - 1;
        float* hB_w = p.hBall + (size_t)((te & 1) ? 63 : 62) * BB * HH;
        float* hB_r = p.hBall + (size_t)((te & 1) ? 62 : 63) * BB * HH;
        const int u0 = (bid - 256) * 4;
        float acc[16] = {0.f};
        lstm_accum(nullptr, nullptr, hA_r, HH, p.enc_wih1, u0, acc, SH);
        lstm_accum(nullptr, nullptr, hB_r, HH, p.enc_whh1, u0, acc, SH);
        lstm_finish(p.enc_b1, u0, acc, p.cB + (bid - 256) * 128, hB_w, SH);
      }
    }
    gbar(p.arr, p.gen, ++gen);
  }

  // ---- decoder with deferred teacher-step FC (flushes of 4 = 2x 2-t passes)
  int pend[4]; int npend = 0;
  for (int k = 0; k < TT - 1; ++k) {
    const int par = k & 1;
    float* hA_r = par ? p.hA0 : p.hA1;    // k=0 -> hA1 (enc final)
    float* hA_w = par ? p.hA1 : p.hA0;
    float* hB_r = p.hBall + (size_t)((k + 63) & 63) * BB * HH;  // k=0 -> slot63
    float* hB_w = p.hBall + (size_t)k * BB * HH;
    const bool teach = (k == 0) || (p.tmask[k] > 0);

    if (!teach) {
      // A: inline FC for logits t=k (needed by this step's argmax)
      if (bid < NFC) fc_dot<1>(p, hB_r, hB_r, k, k, bid, SH, true);
      gbar(p.arr, p.gen, ++gen);
      // B: amred -> p.tok
      if (bid < 32) amred(p, SH);
      gbar(p.arr, p.gen, ++gen);
    }
    // L0 || L1h
    {
      float accB[16];
      if (bid < 256) {
        if (tid < 32) stok[tid] = teach ? p.tgt[tid * TT + k] : ldci(p.tok + tid);
        __syncthreads();
        const int u0 = bid * 4;
        float acc[16] = {0.f};
        lstm_accum(p.dec_embed, stok, nullptr, EE, p.dec_wih0, u0, acc, SH);
        lstm_accum(nullptr, nullptr, hA_r, HH, p.dec_whh0, u0, acc, SH);
        lstm_finish(p.dec_b0, u0, acc, p.cA + bid * 128, hA_w, SH);
      } else {
#pragma unroll
        for (int q = 0; q < 16; ++q) accB[q] = 0.f;
        lstm_accum(nullptr, nullptr, hB_r, HH, p.dec_whh1, (bid - 256) * 4, accB, SH);
      }
      gbar(p.arr, p.gen, ++gen);
      // L1x + cell
      if (bid >= 256) {
        const int u0 = (bid - 256) * 4;
        lstm_accum(nullptr, nullptr, hA_w, HH, p.dec_wih1, u0, accB, SH);
        lstm_finish(p.dec_b1, u0, accB, p.cB + (bid - 256) * 128, hB_w, SH);
      }
      gbar(p.arr, p.gen, ++gen);
    }
    // queue logits t=k+1 (from hB(k)): argmax step inlines; else defer.
    {
      const int nt_ = k + 1;
      const bool nt_inline = (nt_ <= TT - 2) && (p.tmask[nt_] <= 0);
      if (!nt_inline) { pend[npend] = nt_; ++npend; }
      if (npend == 4) {
        if (bid < NFC) {
          fc_dot<2>(p, p.hBall + (size_t)(pend[0]-1) * BB * HH,
                       p.hBall + (size_t)(pend[1]-1) * BB * HH,
                       pend[0], pend[1], bid, SH, false);
          fc_dot<2>(p, p.hBall + (size_t)(pend[2]-1) * BB * HH,
                       p.hBall + (size_t)(pend[3]-1) * BB * HH,
                       pend[2], pend[3], bid, SH, false);
        }
        npend = 0;
        gbar(p.arr, p.gen, ++gen);
      }
    }
  }
  // ---- final flush of remaining deferred logits (includes t=63)
  if (bid < NFC) {
    int i = 0;
    for (; i + 1 < npend; i += 2)
      fc_dot<2>(p, p.hBall + (size_t)(pend[i]-1) * BB * HH,
                   p.hBall + (size_t)(pend[i+1]-1) * BB * HH,
                   pend[i], pend[i+1], bid, SH, false);
    if (i < npend)
      fc_dot<1>(p, p.hBall + (size_t)(pend[i]-1) * BB * HH,
                   p.hBall + (size_t)(pend[i]-1) * BB * HH,
                   pend[i], pend[i], bid, SH, false);
  }
}

// ---------------------------------------------------------------------------
extern "C" void kernel_launch(void* const* d_in, const int* in_sizes, int n_in,
                              void* d_out, int out_size, void* d_ws, size_t ws_size,
                              hipStream_t stream) {
  Par p;
  p.src       = (const int*)d_in[0];
  p.tgt       = (const int*)d_in[1];
  p.tmask     = (const int*)d_in[2];
  p.enc_embed = (const float*)d_in[3];
  p.dec_embed = (const float*)d_in[4];
  p.enc_wih0  = (const float*)d_in[5];
  p.enc_whh0  = (const float*)d_in[6];
  p.enc_b0    = (const float*)d_in[7];
  p.enc_wih1  = (const float*)d_in[8];
  p.enc_whh1  = (const float*)d_in[9];
  p.enc_b1    = (const float*)d_in[10];
  p.dec_wih0  = (const float*)d_in[11];
  p.dec_whh0  = (const float*)d_in[12];
  p.dec_b0    = (const float*)d_in[13];
  p.dec_wih1  = (const float*)d_in[14];
  p.dec_whh1  = (const float*)d_in[15];
  p.dec_b1    = (const float*)d_in[16];
  p.fc_w      = (const float*)d_in[17];
  p.fc_b      = (const float*)d_in[18];
  p.out       = (float*)d_out;

  p.arr = (int*)d_ws;                            // 512 slots x 64B
  p.gen = (int*)((char*)d_ws + 32768);           // 16 slots x 64B
  p.tok = (int*)((char*)d_ws + 34048);           // 32 ints
  float* f = (float*)((char*)d_ws + 36864);
  p.hA0   = f; f += BB * HH;
  p.hA1   = f; f += BB * HH;
  p.hBall = f; f += (size_t)64 * BB * HH;        // 8MB history ring
  p.cA    = f; f += 256 * 128;
  p.cB    = f; f += 256 * 128;
  p.cand  = (float2*)f; f += NFC * 32 * 2;

  hipMemsetAsync(d_ws, 0, 36864, stream);
  mega<<<dim3(GRID), dim3(BLK), 0, stream>>>(p);
}

// Round 12
// 16672.362 us; speedup vs baseline: 1.2805x; 1.2805x over previous
//
#include <hip/hip_runtime.h>

#define BB 32
#define SS 64
#define TT 64
#define VV 32000
#define EE 512
#define HH 1024
#define GRID 512
#define BLK 512
#define NFC 500          // FC tiles of 64 j
#define ASTR 16          // barrier slot stride in ints (64B)
#define FLTMAX 3.402823466e38f

typedef unsigned long long u64;

struct Par {
  const int *src, *tgt, *tmask;
  const float *enc_embed, *dec_embed;
  const float *enc_wih0, *enc_whh0, *enc_b0;
  const float *enc_wih1, *enc_whh1, *enc_b1;
  const float *dec_wih0, *dec_whh0, *dec_b0;
  const float *dec_wih1, *dec_whh1, *dec_b1;
  const float *fc_w, *fc_b;
  float *out;
  float *hA0, *hA1;               // layer-0 h double buffer (coherent)
  float *hBall;                   // 64 slots x [32][1024] h-history (coherent)
  float *cA, *cB;                 // block-private cell state
  float2 *cand;                   // [500][32]
  int *tok;                       // [32]
  int *arr; int *gen;
};

__device__ __forceinline__ float sigf(float x) { return 1.0f / (1.0f + expf(-x)); }

// ---- coherent agent-scope RELAXED access (no L2-invalidate fences) --------
__device__ __forceinline__ float2 ldc2(const float* p) {
  u64 v = __hip_atomic_load((const u64*)p, __ATOMIC_RELAXED, __HIP_MEMORY_SCOPE_AGENT);
  union { u64 u; float2 f; } c; c.u = v; return c.f;
}
__device__ __forceinline__ void stc2(float* p, float x, float y) {
  union { u64 u; float2 f; } c; c.f = make_float2(x, y);
  __hip_atomic_store((u64*)p, c.u, __ATOMIC_RELAXED, __HIP_MEMORY_SCOPE_AGENT);
}
__device__ __forceinline__ void stc1(float* p, float x) {
  __hip_atomic_store(p, x, __ATOMIC_RELAXED, __HIP_MEMORY_SCOPE_AGENT);
}
__device__ __forceinline__ int ldci(const int* p) {
  return __hip_atomic_load(p, __ATOMIC_RELAXED, __HIP_MEMORY_SCOPE_AGENT);
}

// ---------------------------------------------------------------------------
// Fence-free grid barrier: 64B-stride arrival slots, 16 replicated gen lines,
// exponential-backoff polling. REQUIRES all 512 blocks co-resident.
// ---------------------------------------------------------------------------
__device__ __forceinline__ void gbar(int* arr, int* gen, int target) {
  __syncthreads();
  asm volatile("s_waitcnt vmcnt(0)" ::: "memory");
  if (blockIdx.x == 0) {
    if (threadIdx.x < 64) {
      const int s = threadIdx.x;
      int spin = 0;
      for (;;) {
        bool ok = true;
#pragma unroll
        for (int o = 0; o < GRID; o += 64) {
          int idx = s + o;
          int a = (idx == 0) ? target
              : __hip_atomic_load(arr + idx * ASTR, __ATOMIC_RELAXED, __HIP_MEMORY_SCOPE_AGENT);
          ok &= (a >= target);
        }
        if (__all(ok)) break;
        if (spin < 8) __builtin_amdgcn_s_sleep(1);
        else          __builtin_amdgcn_s_sleep(8);
        ++spin;
      }
    }
    __syncthreads();
    if (threadIdx.x < 16)
      __hip_atomic_store(gen + threadIdx.x * ASTR, target, __ATOMIC_RELAXED, __HIP_MEMORY_SCOPE_AGENT);
  } else {
    if (threadIdx.x == 0) {
      __hip_atomic_store(arr + blockIdx.x * ASTR, target, __ATOMIC_RELAXED, __HIP_MEMORY_SCOPE_AGENT);
      int spin = 0;
      while (__hip_atomic_load(gen + (blockIdx.x & 15) * ASTR, __ATOMIC_RELAXED, __HIP_MEMORY_SCOPE_AGENT) < target) {
        if (spin < 4)       __builtin_amdgcn_s_sleep(1);
        else if (spin < 16) __builtin_amdgcn_s_sleep(8);
        else                __builtin_amdgcn_s_sleep(32);
        ++spin;
      }
    }
    __syncthreads();
  }
  asm volatile("" ::: "memory");
}

// ---------------------------------------------------------------------------
// LSTM partial accumulate (u-tile 4 -> 16 gate rows, acc[16]); weights staged
// via LDS (coalesced 1KB/instr), read back as 2-way-broadcast b128 (free).
// Threads: b = tid&31, tc = tid>>5 (16 k-slices of 16 per 256-chunk).
// ---------------------------------------------------------------------------
__device__ __forceinline__ void lstm_accum(
    const float* __restrict__ tab, const int* __restrict__ stokL,
    const float* __restrict__ xcoh, int lenx,
    const float* __restrict__ W, int u0,
    float* __restrict__ acc, float* __restrict__ wbuf)
{
  const int tid = threadIdx.x;
  const int b = tid & 31, tc = tid >> 5;
  const int lane = tid & 63, wid = tid >> 6;
  const int r2 = wid + 8;
  const float* wr1 = W + (size_t)((wid >> 2) * HH + u0 + (wid & 3)) * lenx + (lane << 2);
  const float* wr2 = W + (size_t)((r2  >> 2) * HH + u0 + (r2  & 3)) * lenx + (lane << 2);
  const int ncx = lenx >> 8;
  for (int c = 0; c < ncx; ++c) {
    const int col = c << 8;
    __syncthreads();
    {
      float4 wA = *reinterpret_cast<const float4*>(wr1 + col);
      float4 wB = *reinterpret_cast<const float4*>(wr2 + col);
      *reinterpret_cast<float4*>(wbuf + (wid << 8) + (lane << 2)) = wA;
      *reinterpret_cast<float4*>(wbuf + (r2  << 8) + (lane << 2)) = wB;
    }
    float xr[16];
    if (tab) {
      const int tk = stokL[b];
      if (tk) {
        const float4* s4 = reinterpret_cast<const float4*>(
            tab + (size_t)tk * lenx + col + (tc << 4));
#pragma unroll
        for (int e = 0; e < 4; ++e) {
          float4 v = s4[e];
          xr[e*4] = v.x; xr[e*4+1] = v.y; xr[e*4+2] = v.z; xr[e*4+3] = v.w;
        }
      } else {
#pragma unroll
        for (int e = 0; e < 16; ++e) xr[e] = 0.f;
      }
    } else {
      const float* xp = xcoh + (size_t)b * lenx + col + (tc << 4);
#pragma unroll
      for (int e = 0; e < 8; ++e) {
        float2 v = ldc2(xp + 2*e); xr[2*e] = v.x; xr[2*e+1] = v.y;
      }
    }
    __syncthreads();
#pragma unroll
    for (int q = 0; q < 16; ++q) {
      const float4* w4 = reinterpret_cast<const float4*>(wbuf + (q << 8) + (tc << 4));
      float4 w0 = w4[0], w1 = w4[1], w2 = w4[2], w3 = w4[3];
      acc[q] += xr[0]*w0.x + xr[1]*w0.y + xr[2]*w0.z + xr[3]*w0.w
              + xr[4]*w1.x + xr[5]*w1.y + xr[6]*w1.z + xr[7]*w1.w
              + xr[8]*w2.x + xr[9]*w2.y + xr[10]*w2.z + xr[11]*w2.w
              + xr[12]*w3.x + xr[13]*w3.y + xr[14]*w3.z + xr[15]*w3.w;
    }
  }
}

// cross-slice reduce + cell + coherent h-store (red at SH+4096)
__device__ __forceinline__ void lstm_finish(
    const float* __restrict__ bias, int u0,
    const float* __restrict__ acc, float* __restrict__ cpriv,
    float* __restrict__ hdst, float* __restrict__ SH)
{
  const int tid = threadIdx.x;
  const int b = tid & 31, tc = tid >> 5;
  float* red = SH + 4096;
  __syncthreads();
#pragma unroll
  for (int q = 0; q < 16; ++q) red[(tc * 16 + q) * 33 + b] = acc[q];
  __syncthreads();
  if (tid < 128) {
    int bb = tid & 31, ul = tid >> 5;
    float g[4];
#pragma unroll
    for (int gg = 0; gg < 4; ++gg) {
      float s = bias[gg * HH + u0 + ul];
#pragma unroll
      for (int t2 = 0; t2 < 16; ++t2) s += red[(t2 * 16 + gg * 4 + ul) * 33 + bb];
      g[gg] = s;
    }
    float cn = sigf(g[1]) * cpriv[(bb << 2) + ul] + sigf(g[0]) * tanhf(g[2]);
    float hn = sigf(g[3]) * tanhf(cn);
    cpriv[(bb << 2) + ul] = cn;
    stc1(hdst + (size_t)bb * HH + u0 + ul, hn);
  }
  __syncthreads();
}

// ---------------------------------------------------------------------------
// FC tile, NT time-steps per pass (weights reused in REGISTERS across t).
// Thread: jl=tid&15 -> 4 j's; bg=(tid>>4)&15 -> 2 b's; kh=tid>>8 -> k-half of
// each 128-chunk. acc[8*NT] (<=16). Plain cached weight loads, lane-distinct
// rows. h broadcast from LDS [32][136] per t. do_am reduces t0's argmax.
// ---------------------------------------------------------------------------
template<int NT>
__device__ __forceinline__ void fc_dot(const Par& p,
    const float* __restrict__ h0, const float* __restrict__ h1,
    int t0, int t1, int fcid, float* __restrict__ SH, bool do_am)
{
  const int tid = threadIdx.x;
  const int jl = tid & 15;
  const int bg = (tid >> 4) & 15;
  const int kh = tid >> 8;
  const int jbase = fcid * 64;
  const int j0 = jbase + (jl << 2);
  const float* w0 = p.fc_w + (size_t)j0 * HH;
  const float* w1 = w0 + HH;
  const float* w2 = w1 + HH;
  const float* w3 = w2 + HH;
  float acc[8 * NT];
#pragma unroll
  for (int q = 0; q < 8 * NT; ++q) acc[q] = 0.f;

  for (int c = 0; c < 8; ++c) {
    __syncthreads();
    {   // stage [32][128] per t -> SH[t*4352 + row*136 + col]
      int sb = tid >> 4, cg = (tid & 15) << 3;
      const float* xp0 = h0 + (size_t)sb * HH + (c << 7) + cg;
      float* d0 = SH + sb * 136 + cg;
#pragma unroll
      for (int e = 0; e < 4; ++e) {
        float2 v = ldc2(xp0 + 2 * e); d0[2*e] = v.x; d0[2*e+1] = v.y;
      }
      if constexpr (NT == 2) {
        const float* xp1 = h1 + (size_t)sb * HH + (c << 7) + cg;
        float* d1 = SH + 4352 + sb * 136 + cg;
#pragma unroll
        for (int e = 0; e < 4; ++e) {
          float2 v = ldc2(xp1 + 2 * e); d1[2*e] = v.x; d1[2*e+1] = v.y;
        }
      }
    }
    __syncthreads();
    const int kb = (c << 7) + (kh << 6);
    const float* pw0 = w0 + kb; const float* pw1 = w1 + kb;
    const float* pw2 = w2 + kb; const float* pw3 = w3 + kb;
    const float* px0 = SH + ((bg << 1) * 136) + (kh << 6);
    const float* px1 = SH + 4352 + ((bg << 1) * 136) + (kh << 6);
#pragma unroll 4
    for (int kk = 0; kk < 64; kk += 4) {
      float4 a0 = *reinterpret_cast<const float4*>(pw0 + kk);
      float4 a1 = *reinterpret_cast<const float4*>(pw1 + kk);
      float4 a2 = *reinterpret_cast<const float4*>(pw2 + kk);
      float4 a3 = *reinterpret_cast<const float4*>(pw3 + kk);
      float4 xA = *reinterpret_cast<const float4*>(px0 + kk);
      float4 xB = *reinterpret_cast<const float4*>(px0 + 136 + kk);
      acc[0] += a0.x*xA.x + a0.y*xA.y + a0.z*xA.z + a0.w*xA.w;
      acc[1] += a1.x*xA.x + a1.y*xA.y + a1.z*xA.z + a1.w*xA.w;
      acc[2] += a2.x*xA.x + a2.y*xA.y + a2.z*xA.z + a2.w*xA.w;
      acc[3] += a3.x*xA.x + a3.y*xA.y + a3.z*xA.z + a3.w*xA.w;
      acc[4] += a0.x*xB.x + a0.y*xB.y + a0.z*xB.z + a0.w*xB.w;
      acc[5] += a1.x*xB.x + a1.y*xB.y + a1.z*xB.z + a1.w*xB.w;
      acc[6] += a2.x*xB.x + a2.y*xB.y + a2.z*xB.z + a2.w*xB.w;
      acc[7] += a3.x*xB.x + a3.y*xB.y + a3.z*xB.z + a3.w*xB.w;
      if constexpr (NT == 2) {
        float4 yA = *reinterpret_cast<const float4*>(px1 + kk);
        float4 yB = *reinterpret_cast<const float4*>(px1 + 136 + kk);
        acc[8]  += a0.x*yA.x + a0.y*yA.y + a0.z*yA.z + a0.w*yA.w;
        acc[9]  += a1.x*yA.x + a1.y*yA.y + a1.z*yA.z + a1.w*yA.w;
        acc[10] += a2.x*yA.x + a2.y*yA.y + a2.z*yA.z + a2.w*yA.w;
        acc[11] += a3.x*yA.x + a3.y*yA.y + a3.z*yA.z + a3.w*yA.w;
        acc[12] += a0.x*yB.x + a0.y*yB.y + a0.z*yB.z + a0.w*yB.w;
        acc[13] += a1.x*yB.x + a1.y*yB.y + a1.z*yB.z + a1.w*yB.w;
        acc[14] += a2.x*yB.x + a2.y*yB.y + a2.z*yB.z + a2.w*yB.w;
        acc[15] += a3.x*yB.x + a3.y*yB.y + a3.z*yB.z + a3.w*yB.w;
      }
    }
  }
  // k-half reduce at SH+8704 [256][17]
  float* red2 = SH + 8704;
  __syncthreads();
  if (kh == 1) {
    int s = tid - 256;
#pragma unroll
    for (int e = 0; e < 8 * NT; ++e) red2[s * 17 + e] = acc[e];
  }
  __syncthreads();
  if (kh == 0) {
#pragma unroll
    for (int e = 0; e < 8 * NT; ++e) acc[e] += red2[tid * 17 + e];
    float b0 = p.fc_b[j0], b1 = p.fc_b[j0+1], b2 = p.fc_b[j0+2], b3 = p.fc_b[j0+3];
    const int rb0 = bg << 1, rb1 = rb0 + 1;
    float4 vA = make_float4(acc[0]+b0, acc[1]+b1, acc[2]+b2, acc[3]+b3);
    float4 vB = make_float4(acc[4]+b0, acc[5]+b1, acc[6]+b2, acc[7]+b3);
    *reinterpret_cast<float4*>(p.out + (size_t)rb0 * TT * VV + (size_t)t0 * VV + j0) = vA;
    *reinterpret_cast<float4*>(p.out + (size_t)rb1 * TT * VV + (size_t)t0 * VV + j0) = vB;
    if constexpr (NT == 2) {
      float4 wA = make_float4(acc[8]+b0, acc[9]+b1, acc[10]+b2, acc[11]+b3);
      float4 wB = make_float4(acc[12]+b0, acc[13]+b1, acc[14]+b2, acc[15]+b3);
      *reinterpret_cast<float4*>(p.out + (size_t)rb0 * TT * VV + (size_t)t1 * VV + j0) = wA;
      *reinterpret_cast<float4*>(p.out + (size_t)rb1 * TT * VV + (size_t)t1 * VV + j0) = wB;
    }
    if (do_am) {   // per-(b, jl) first-max over this thread's 4 j (t0 only)
      float2* SA = reinterpret_cast<float2*>(SH + 13056);   // [32][16]
      float mA = acc[0] + b0; int iA = j0;
      if (acc[1]+b1 > mA) { mA = acc[1]+b1; iA = j0+1; }
      if (acc[2]+b2 > mA) { mA = acc[2]+b2; iA = j0+2; }
      if (acc[3]+b3 > mA) { mA = acc[3]+b3; iA = j0+3; }
      float mB = acc[4] + b0; int iB = j0;
      if (acc[5]+b1 > mB) { mB = acc[5]+b1; iB = j0+1; }
      if (acc[6]+b2 > mB) { mB = acc[6]+b2; iB = j0+2; }
      if (acc[7]+b3 > mB) { mB = acc[7]+b3; iB = j0+3; }
      SA[rb0 * 16 + jl] = make_float2(mA, __int_as_float(iA));
      SA[rb1 * 16 + jl] = make_float2(mB, __int_as_float(iB));
    }
  }
  __syncthreads();
  if (do_am && tid < 32) {
    float2* SA = reinterpret_cast<float2*>(SH + 13056);
    float bv = -FLTMAX; int bi = 0x7fffffff;
#pragma unroll
    for (int s2 = 0; s2 < 16; ++s2) {
      float2 cv = SA[tid * 16 + s2]; int ci = __float_as_int(cv.y);
      if (cv.x > bv || (cv.x == bv && ci < bi)) { bv = cv.x; bi = ci; }
    }
    stc2((float*)&p.cand[fcid * 32 + tid], bv, __int_as_float(bi));
  }
  __syncthreads();
}

// AMred: block b (0..31) reduces 500 candidates -> p.tok[b] (argmax steps only)
__device__ __forceinline__ void amred(const Par& p, float* SH)
{
  const int tid = threadIdx.x;
  const int b = blockIdx.x;
  float bv = -FLTMAX; int bi = 0x7fffffff;
  if (tid < NFC) {
    float2 cv = ldc2((const float*)&p.cand[tid * 32 + b]);
    bv = cv.x; bi = __float_as_int(cv.y);
  }
  float* sv = SH; int* si = (int*)(SH + 512);
  sv[tid] = bv; si[tid] = bi;
  __syncthreads();
  for (int s = 256; s > 0; s >>= 1) {
    if (tid < s) {
      float ov = sv[tid + s]; int oi = si[tid + s];
      if (ov > sv[tid] || (ov == sv[tid] && oi < si[tid])) { sv[tid] = ov; si[tid] = oi; }
    }
    __syncthreads();
  }
  if (tid == 0)
    __hip_atomic_store(p.tok + b, si[0], __ATOMIC_RELAXED, __HIP_MEMORY_SCOPE_AGENT);
}

// ---------------------------------------------------------------------------
__global__ __launch_bounds__(BLK, 4) void mega(Par p) {
  __shared__ __attribute__((aligned(16))) float SH[14336];  // 57.3KB -> 2 blocks/CU
  __shared__ int stok[32];

  const int tid = threadIdx.x;
  const int bid = blockIdx.x;
  const int gid = bid * BLK + tid;
  int gen = 0;

  // ---- init
  for (int i = gid * 2; i < 2 * BB * HH; i += GRID * BLK * 2)
    stc2(p.hA0 + i, 0.f, 0.f);                       // hA0,hA1 contiguous
  for (int i = gid * 2; i < 2 * BB * HH; i += GRID * BLK * 2)
    stc2(p.hBall + 62 * BB * HH + i, 0.f, 0.f);      // hB slots 62,63 (enc ping-pong)
  if (tid < 128) {
    if (bid < 256) p.cA[bid * 128 + tid] = 0.f;
    else           p.cB[(bid - 256) * 128 + tid] = 0.f;
  }
  for (long g2 = gid; g2 < (long)BB * VV; g2 += (long)GRID * BLK) {
    int b = (int)(g2 / VV), v = (int)(g2 - (long)b * VV);
    __builtin_nontemporal_store(0.f, p.out + (size_t)b * TT * VV + v);
  }
  gbar(p.arr, p.gen, ++gen);

  // ---- encoder: L0(tt) on blocks 0..255 || L1(tt-1) on 256..511
  for (int tt = 0; tt <= SS; ++tt) {
    const int par = tt & 1;
    float* hA_w = par ? p.hA1 : p.hA0;
    float* hA_r = par ? p.hA0 : p.hA1;
    if (bid < 256) {
      if (tt < SS) {
        if (tid < 32) stok[tid] = p.src[tid * SS + tt];
        __syncthreads();
        const int u0 = bid * 4;
        float acc[16] = {0.f};
        lstm_accum(p.enc_embed, stok, nullptr, EE, p.enc_wih0, u0, acc, SH);
        lstm_accum(nullptr, nullptr, hA_r, HH, p.enc_whh0, u0, acc, SH);
        lstm_finish(p.enc_b0, u0, acc, p.cA + bid * 128, hA_w, SH);
      }
    } else {
      if (tt >= 1) {
        const int te = tt - 1;
        float* hB_w = p.hBall + (size_t)((te & 1) ? 63 : 62) * BB * HH;
        float* hB_r = p.hBall + (size_t)((te & 1) ? 62 : 63) * BB * HH;
        const int u0 = (bid - 256) * 4;
        float acc[16] = {0.f};
        lstm_accum(nullptr, nullptr, hA_r, HH, p.enc_wih1, u0, acc, SH);
        lstm_accum(nullptr, nullptr, hB_r, HH, p.enc_whh1, u0, acc, SH);
        lstm_finish(p.enc_b1, u0, acc, p.cB + (bid - 256) * 128, hB_w, SH);
      }
    }
    gbar(p.arr, p.gen, ++gen);
  }

  // ---- decoder; teacher-step FCs deferred and paired (argmax steps absorb one)
  int pend[4]; int npend = 0;
  for (int k = 0; k < TT - 1; ++k) {
    const int par = k & 1;
    float* hA_r = par ? p.hA0 : p.hA1;    // k=0 -> hA1 (enc final)
    float* hA_w = par ? p.hA1 : p.hA0;
    float* hB_r = p.hBall + (size_t)((k + 63) & 63) * BB * HH;  // k=0 -> slot63
    float* hB_w = p.hBall + (size_t)k * BB * HH;
    const bool teach = (k == 0) || (p.tmask[k] > 0);

    if (!teach) {
      // A: inline FC for logits t=k (argmax input); absorb one pending step
      if (npend > 0) {
        const int tq = pend[0];
        pend[0] = pend[1]; pend[1] = pend[2]; pend[2] = pend[3];
        --npend;
        if (bid < NFC)
          fc_dot<2>(p, hB_r, p.hBall + (size_t)(tq - 1) * BB * HH, k, tq, bid, SH, true);
      } else {
        if (bid < NFC)
          fc_dot<1>(p, hB_r, hB_r, k, k, bid, SH, true);
      }
      gbar(p.arr, p.gen, ++gen);
      // B: amred -> p.tok
      if (bid < 32) amred(p, SH);
      gbar(p.arr, p.gen, ++gen);
    }
    // L0 || L1h
    {
      float accB[16];
      if (bid < 256) {
        if (tid < 32) stok[tid] = teach ? p.tgt[tid * TT + k] : ldci(p.tok + tid);
        __syncthreads();
        const int u0 = bid * 4;
        float acc[16] = {0.f};
        lstm_accum(p.dec_embed, stok, nullptr, EE, p.dec_wih0, u0, acc, SH);
        lstm_accum(nullptr, nullptr, hA_r, HH, p.dec_whh0, u0, acc, SH);
        lstm_finish(p.dec_b0, u0, acc, p.cA + bid * 128, hA_w, SH);
      } else {
#pragma unroll
        for (int q = 0; q < 16; ++q) accB[q] = 0.f;
        lstm_accum(nullptr, nullptr, hB_r, HH, p.dec_whh1, (bid - 256) * 4, accB, SH);
      }
      gbar(p.arr, p.gen, ++gen);
      // L1x + cell
      if (bid >= 256) {
        const int u0 = (bid - 256) * 4;
        lstm_accum(nullptr, nullptr, hA_w, HH, p.dec_wih1, u0, accB, SH);
        lstm_finish(p.dec_b1, u0, accB, p.cB + (bid - 256) * 128, hB_w, SH);
      }
      gbar(p.arr, p.gen, ++gen);
    }
    // queue logits t=k+1 (from hB(k)): argmax step inlines; else defer.
    {
      const int nt_ = k + 1;
      const bool nt_inline = (nt_ <= TT - 2) && (p.tmask[nt_] <= 0);
      if (!nt_inline) { pend[npend] = nt_; ++npend; }
      if (npend == 4) {
        if (bid < NFC) {
          fc_dot<2>(p, p.hBall + (size_t)(pend[0]-1) * BB * HH,
                       p.hBall + (size_t)(pend[1]-1) * BB * HH,
                       pend[0], pend[1], bid, SH, false);
          fc_dot<2>(p, p.hBall + (size_t)(pend[2]-1) * BB * HH,
                       p.hBall + (size_t)(pend[3]-1) * BB * HH,
                       pend[2], pend[3], bid, SH, false);
        }
        npend = 0;
        gbar(p.arr, p.gen, ++gen);
      }
    }
  }
  // ---- final flush of remaining deferred logits (includes t=63)
  if (bid < NFC) {
    int i = 0;
    for (; i + 1 < npend; i += 2)
      fc_dot<2>(p, p.hBall + (size_t)(pend[i]-1) * BB * HH,
                   p.hBall + (size_t)(pend[i+1]-1) * BB * HH,
                   pend[i], pend[i+1], bid, SH, false);
    if (i < npend)
      fc_dot<1>(p, p.hBall + (size_t)(pend[i]-1) * BB * HH,
                   p.hBall + (size_t)(pend[i]-1) * BB * HH,
                   pend[i], pend[i], bid, SH, false);
  }
}

// ---------------------------------------------------------------------------
extern "C" void kernel_launch(void* const* d_in, const int* in_sizes, int n_in,
                              void* d_out, int out_size, void* d_ws, size_t ws_size,
                              hipStream_t stream) {
  Par p;
  p.src       = (const int*)d_in[0];
  p.tgt       = (const int*)d_in[1];
  p.tmask     = (const int*)d_in[2];
  p.enc_embed = (const float*)d_in[3];
  p.dec_embed = (const float*)d_in[4];
  p.enc_wih0  = (const float*)d_in[5];
  p.enc_whh0  = (const float*)d_in[6];
  p.enc_b0    = (const float*)d_in[7];
  p.enc_wih1  = (const float*)d_in[8];
  p.enc_whh1  = (const float*)d_in[9];
  p.enc_b1    = (const float*)d_in[10];
  p.dec_wih0  = (const float*)d_in[11];
  p.dec_whh0  = (const float*)d_in[12];
  p.dec_b0    = (const float*)d_in[13];
  p.dec_wih1  = (const float*)d_in[14];
  p.dec_whh1  = (const float*)d_in[15];
  p.dec_b1    = (const float*)d_in[16];
  p.fc_w      = (const float*)d_in[17];
  p.fc_b      = (const float*)d_in[18];
  p.out       = (float*)d_out;

  p.arr = (int*)d_ws;                            // 512 slots x 64B
  p.gen = (int*)((char*)d_ws + 32768);           // 16 slots x 64B
  p.tok = (int*)((char*)d_ws + 34048);           // 32 ints
  float* f = (float*)((char*)d_ws + 36864);
  p.hA0   = f; f += BB * HH;
  p.hA1   = f; f += BB * HH;
  p.hBall = f; f += (size_t)64 * BB * HH;        // 8MB history ring
  p.cA    = f; f += 256 * 128;
  p.cB    = f; f += 256 * 128;
  p.cand  = (float2*)f; f += NFC * 32 * 2;

  hipMemsetAsync(d_ws, 0, 36864, stream);
  mega<<<dim3(GRID), dim3(BLK), 0, stream>>>(p);
}